// Round 8
// baseline (325.455 us; speedup 1.0000x reference)
//
#include <hip/hip_runtime.h>

typedef unsigned short u16;
typedef __attribute__((ext_vector_type(8))) short bf16x8;
typedef __attribute__((ext_vector_type(4))) float f32x4;

__device__ __forceinline__ u16 f2bf(float f) {
  unsigned u = __builtin_bit_cast(unsigned, f);
  u += 0x7fffu + ((u >> 16) & 1u);
  return (u16)(u >> 16);
}

__device__ __forceinline__ unsigned pkbf(float lo, float hi) {
  unsigned r;
  asm("v_cvt_pk_bf16_f32 %0, %1, %2" : "=v"(r) : "v"(lo), "v"(hi));
  return r;
}

__device__ __forceinline__ void gll16(const void* g, void* l) {
  __builtin_amdgcn_global_load_lds((const __attribute__((address_space(1))) void*)g,
                                   (__attribute__((address_space(3))) void*)l, 16, 0, 0);
}

// ---------------- x -> bf16 (one-time) ----------------
__global__ void xbf_k(const float* __restrict__ x, u16* __restrict__ xb) {
  const size_t i = ((size_t)blockIdx.x * 256 + threadIdx.x) * 8;
  float4 a = *(const float4*)(x + i);
  float4 b = *(const float4*)(x + i + 4);
  uint4 u;
  u.x = pkbf(a.x, a.y);
  u.y = pkbf(a.z, a.w);
  u.z = pkbf(b.x, b.y);
  u.w = pkbf(b.z, b.w);
  *(uint4*)(xb + i) = u;
}

// ---------------- bias concat: bc[1280] = [bq | bk | bv] ----------------
__global__ void build_bias_k(const float* __restrict__ bq, const float* __restrict__ bk,
                             const float* __restrict__ bv, float* __restrict__ bc) {
  int i = blockIdx.x * 256 + threadIdx.x;
  if (i < 1280) bc[i] = (i < 128) ? bq[i] : ((i < 256) ? bk[i - 128] : bv[i - 256]);
}

// ------- weight transpose: wt[n][f] bf16, n in [0,1280), f in [0,1024) -------
__global__ void transpose_w_k(const float* __restrict__ Wq, const float* __restrict__ Wk,
                              const float* __restrict__ Wv, u16* __restrict__ wt) {
  __shared__ float tile[64][65];
  const int n0 = blockIdx.x * 64;
  const int f0 = blockIdx.y * 64;
  const int t = threadIdx.x;
  const float* src; int ld, coff;
  if (n0 < 128)      { src = Wq; ld = 128;  coff = n0; }
  else if (n0 < 256) { src = Wk; ld = 128;  coff = n0 - 128; }
  else               { src = Wv; ld = 1024; coff = n0 - 256; }
  const int r = t >> 4, c4 = (t & 15) * 4;
  #pragma unroll
  for (int i = 0; i < 4; ++i) {
    float4 v = *(const float4*)(src + (size_t)(f0 + r + 16 * i) * ld + coff + c4);
    tile[r + 16 * i][c4 + 0] = v.x;
    tile[r + 16 * i][c4 + 1] = v.y;
    tile[r + 16 * i][c4 + 2] = v.z;
    tile[r + 16 * i][c4 + 3] = v.w;
  }
  __syncthreads();
  #pragma unroll
  for (int i = 0; i < 4; ++i) {
    const int nr = r + 16 * i;
    ushort4 h;
    h.x = f2bf(tile[c4 + 0][nr]);
    h.y = f2bf(tile[c4 + 1][nr]);
    h.z = f2bf(tile[c4 + 2][nr]);
    h.w = f2bf(tile[c4 + 3][nr]);
    *(ushort4*)(wt + (size_t)(n0 + nr) * 1024 + f0 + c4) = h;
  }
}

// ---------------- fused QKV GEMM: [32768,1024]bf16 @ [1024,1280] + bias ----------------
__global__ __launch_bounds__(256, 2) void gemm_qkv_k(
    const u16* __restrict__ xb, const u16* __restrict__ wt,
    const float* __restrict__ bc, u16* __restrict__ qkv, u16* __restrict__ vt) {
  __shared__ u16 sA[2 * 128 * 64];
  __shared__ u16 sB[2 * 128 * 64];
  char* sAc = (char*)sA;
  char* sBc = (char*)sB;
  const int t = threadIdx.x;
  const int w = t >> 6, lane = t & 63;
  const int wr = w >> 1, wc = w & 1;
  const int lm = lane & 15, lg = lane >> 4;
  const int bid = blockIdx.x;
  const int mb = ((bid & ~15) >> 1) | (bid & 7);  // 0..255
  const int yg = (bid >> 3) & 1;
  const int m0 = mb * 128;
  const f32x4 FZ = {0.f, 0.f, 0.f, 0.f};

  const int brow = t >> 3;
  const int bcol = 8 * ((t & 7) ^ ((t >> 3) & 7));
  const int kswz = (lm & 7) << 4;
  const u16* ab = xb + (size_t)(m0 + brow) * 1024 + bcol;

  for (int nt = yg * 5; nt < yg * 5 + 5; ++nt) {
    const int n0 = nt * 128;
    f32x4 acc[4][4];
    #pragma unroll
    for (int mi = 0; mi < 4; ++mi)
      #pragma unroll
      for (int ni = 0; ni < 4; ++ni) acc[mi][ni] = FZ;
    const u16* wb = wt + (size_t)(n0 + brow) * 1024 + bcol;

    auto stage = [&](int buf, int k0) {
      char* da = sAc + buf * 16384 + w * 1024;
      char* db = sBc + buf * 16384 + w * 1024;
      #pragma unroll
      for (int i = 0; i < 4; ++i) {
        gll16(ab + (size_t)(32 * i) * 1024 + k0, da + 4096 * i);
        gll16(wb + (size_t)(32 * i) * 1024 + k0, db + 4096 * i);
      }
    };

    int buf = 0;
    stage(0, 0);
    for (int kt = 0; kt < 16; ++kt) {
      __builtin_amdgcn_s_barrier();
      __builtin_amdgcn_sched_barrier(0);
      if (kt < 15) {
        stage(buf ^ 1, (kt + 1) * 64);
        asm volatile("s_waitcnt vmcnt(8)" ::: "memory");
      } else {
        asm volatile("s_waitcnt vmcnt(0)" ::: "memory");
      }
      __builtin_amdgcn_sched_barrier(0);
      __builtin_amdgcn_s_barrier();

      const char* sAb = sAc + buf * 16384;
      const char* sBb = sBc + buf * 16384;
      #pragma unroll
      for (int ks = 0; ks < 2; ++ks) {
        const int ka = (ks * 64 + lg * 16) ^ kswz;
        bf16x8 aF[4], bF[4];
        #pragma unroll
        for (int mi = 0; mi < 4; ++mi)
          aF[mi] = *(const bf16x8*)(sAb + (wr * 64 + mi * 16 + lm) * 128 + ka);
        #pragma unroll
        for (int ni = 0; ni < 4; ++ni)
          bF[ni] = *(const bf16x8*)(sBb + (wc * 64 + ni * 16 + lm) * 128 + ka);
        #pragma unroll
        for (int mi = 0; mi < 4; ++mi)
          #pragma unroll
          for (int ni = 0; ni < 4; ++ni)
            acc[mi][ni] = __builtin_amdgcn_mfma_f32_16x16x32_bf16(aF[mi], bF[ni], acc[mi][ni], 0, 0, 0);
      }
      buf ^= 1;
    }

    #pragma unroll
    for (int ni = 0; ni < 4; ++ni) {
      const int col = n0 + wc * 64 + ni * 16 + lm;
      const float bias = bc[col];
      if (n0 < 256) {
        #pragma unroll
        for (int mi = 0; mi < 4; ++mi) {
          const int r0 = m0 + wr * 64 + mi * 16 + lg * 4;
          #pragma unroll
          for (int j = 0; j < 4; ++j)
            qkv[(size_t)(r0 + j) * 256 + col] = f2bf(acc[mi][ni][j] + bias);
        }
      } else {
        const int h = col - 256;
        #pragma unroll
        for (int mi = 0; mi < 4; ++mi) {
          const int r0 = m0 + wr * 64 + mi * 16 + lg * 4;
          const int bg = r0 >> 10;
          const int sb = r0 & 1023;
          ushort4 pk;
          pk.x = f2bf(acc[mi][ni][0] + bias);
          pk.y = f2bf(acc[mi][ni][1] + bias);
          pk.z = f2bf(acc[mi][ni][2] + bias);
          pk.w = f2bf(acc[mi][ni][3] + bias);
          *(ushort4*)(vt + ((size_t)(bg * 1024 + h) << 10) + sb) = pk;
        }
      }
    }
  }
}

// ---------------- QK^T + exact softmax -> normalized P (bf16) ----------------
__global__ __launch_bounds__(512, 2) void qks_k(const u16* __restrict__ qk,
                                                u16* __restrict__ P) {
  __shared__ float smax[8][32];
  __shared__ float ssum[8][32];
  const int t = threadIdx.x;
  const int w = t >> 6, lane = t & 63;
  const int lm = lane & 15, lg = lane >> 4;
  const int bid = blockIdx.x;
  const int qt = (bid >> 3) & 31;
  const int bg = (((bid >> 8) & 3) << 3) | (bid & 7);
  const f32x4 FZ = {0.f, 0.f, 0.f, 0.f};

  bf16x8 qf[2][4];
  #pragma unroll
  for (int qc = 0; qc < 2; ++qc)
    #pragma unroll
    for (int ks = 0; ks < 4; ++ks)
      qf[qc][ks] = *(const bf16x8*)(qk +
          (size_t)(bg * 1024 + qt * 32 + qc * 16 + lm) * 256 + ks * 32 + lg * 8);

  f32x4 sc[8][2];
  #pragma unroll
  for (int ch = 0; ch < 8; ++ch) { sc[ch][0] = FZ; sc[ch][1] = FZ; }
  const u16* kbase = qk + (size_t)(bg * 1024 + w * 128) * 256 + 128;
  #pragma unroll
  for (int ch = 0; ch < 8; ++ch) {
    bf16x8 kf[4];
    #pragma unroll
    for (int ks = 0; ks < 4; ++ks)
      kf[ks] = *(const bf16x8*)(kbase + (size_t)(ch * 16 + lm) * 256 + ks * 32 + lg * 8);
    #pragma unroll
    for (int ks = 0; ks < 4; ++ks) {
      sc[ch][0] = __builtin_amdgcn_mfma_f32_16x16x32_bf16(kf[ks], qf[0][ks], sc[ch][0], 0, 0, 0);
      sc[ch][1] = __builtin_amdgcn_mfma_f32_16x16x32_bf16(kf[ks], qf[1][ks], sc[ch][1], 0, 0, 0);
    }
  }

  float mx[2];
  #pragma unroll
  for (int qc = 0; qc < 2; ++qc) {
    float m = sc[0][qc][0];
    #pragma unroll
    for (int ch = 0; ch < 8; ++ch)
      #pragma unroll
      for (int j = 0; j < 4; ++j) m = fmaxf(m, sc[ch][qc][j]);
    m = fmaxf(m, __shfl_xor(m, 16));
    m = fmaxf(m, __shfl_xor(m, 32));
    mx[qc] = m;
  }
  if (lg == 0) { smax[w][lm] = mx[0]; smax[w][16 + lm] = mx[1]; }
  __syncthreads();
  float gm[2];
  #pragma unroll
  for (int qc = 0; qc < 2; ++qc) {
    float m = smax[0][qc * 16 + lm];
    #pragma unroll
    for (int wp = 1; wp < 8; ++wp) m = fmaxf(m, smax[wp][qc * 16 + lm]);
    gm[qc] = m;
  }

  float ls[2] = {0.f, 0.f};
  #pragma unroll
  for (int ch = 0; ch < 8; ++ch)
    #pragma unroll
    for (int qc = 0; qc < 2; ++qc) {
      f32x4 e;
      #pragma unroll
      for (int j = 0; j < 4; ++j) e[j] = __expf(sc[ch][qc][j] - gm[qc]);
      sc[ch][qc] = e;
      ls[qc] += (e[0] + e[1]) + (e[2] + e[3]);
    }
  #pragma unroll
  for (int qc = 0; qc < 2; ++qc) {
    ls[qc] += __shfl_xor(ls[qc], 16);
    ls[qc] += __shfl_xor(ls[qc], 32);
  }
  if (lg == 0) { ssum[w][lm] = ls[0]; ssum[w][16 + lm] = ls[1]; }
  __syncthreads();
  float inv[2];
  #pragma unroll
  for (int qc = 0; qc < 2; ++qc) {
    float s = ssum[0][qc * 16 + lm];
    #pragma unroll
    for (int wp = 1; wp < 8; ++wp) s += ssum[wp][qc * 16 + lm];
    inv[qc] = 1.0f / s;
  }

  #pragma unroll
  for (int qc = 0; qc < 2; ++qc) {
    u16* pr = P + ((size_t)(bg * 1024 + qt * 32 + qc * 16 + lm) << 10) + w * 128 + lg * 4;
    #pragma unroll
    for (int ch = 0; ch < 8; ++ch) {
      uint2 u;
      u.x = pkbf(sc[ch][qc][0] * inv[qc], sc[ch][qc][1] * inv[qc]);
      u.y = pkbf(sc[ch][qc][2] * inv[qc], sc[ch][qc][3] * inv[qc]);
      *(uint2*)(pr + ch * 16) = u;
    }
  }
}

// ---------------- PV GEMM + epilogue: out = gamma * (P @ V) + x ----------------
// 8-phase 256x256x64 template (m201 port): 512 thr = 8 waves (2x4), wave tile 128x64,
// per-phase {ds_read subtile + 2 gll16 prefetch -> barrier -> lgkmcnt(0) -> 16 MFMA -> barrier},
// one counted vmcnt per K-tile. LDS 128KB dbuf, XOR-swizzled reads, pre-swizzled gll16 source.
__global__ __launch_bounds__(512, 2) void pv_k(
    const u16* __restrict__ P, const u16* __restrict__ vt,
    const float* __restrict__ x, const float* __restrict__ gam,
    float* __restrict__ out) {
  __shared__ u16 sA[2 * 256 * 64];   // 64 KB
  __shared__ u16 sB[2 * 256 * 64];   // 64 KB
  char* sAc = (char*)sA;
  char* sBc = (char*)sB;
  const int t = threadIdx.x;
  const int w = t >> 6, lane = t & 63;
  const int wr = w >> 2, wc = w & 3;           // 2 x 4 wave grid
  const int lm = lane & 15, lg = lane >> 4;
  const int bid = blockIdx.x;
  const int g2 = (bid & 7) * 64 + (bid >> 3);  // XCD-grouped: 4 bgs per XCD
  const int bg = g2 >> 4;
  const int wi = g2 & 15;
  const int m0 = bg * 1024 + (wi >> 2) * 256;  // global row
  const int n0 = (wi & 3) * 256;
  const f32x4 FZ = {0.f, 0.f, 0.f, 0.f};
  const int kswz = (lm & 7) << 4;

  // staging: sweep p covers rows p*64 + (t>>3); source col pre-swizzled by row&7
  const int srow = t >> 3;
  const int scol = 8 * ((t & 7) ^ ((t >> 3) & 7));
  const u16* pa = P + (size_t)(m0 + srow) * 1024 + scol;
  const u16* pb = vt + (size_t)(bg * 1024 + n0 + srow) * 1024 + scol;

  f32x4 acc[8][4];
  #pragma unroll
  for (int mi = 0; mi < 8; ++mi)
    #pragma unroll
    for (int ni = 0; ni < 4; ++ni) acc[mi][ni] = FZ;

  // prologue: stage tile 0 into buf 0
  #pragma unroll
  for (int p = 0; p < 4; ++p) {
    gll16(pa + (size_t)(p * 64) * 1024, sAc + p * 8192 + t * 16);
    gll16(pb + (size_t)(p * 64) * 1024, sBc + p * 8192 + t * 16);
  }
  asm volatile("s_waitcnt vmcnt(0)" ::: "memory");
  __builtin_amdgcn_s_barrier();

  int buf = 0;
  for (int kt = 0; kt < 16; ++kt) {
    const int k0n = (kt + 1) * 64;           // next tile's k offset
    const char* sAb = sAc + buf * 32768;
    const char* sBb = sBc + buf * 32768;
    char* dAn = sAc + (buf ^ 1) * 32768;
    char* dBn = sBc + (buf ^ 1) * 32768;
    bf16x8 bF[4];
    #pragma unroll
    for (int p = 0; p < 4; ++p) {
      const int ks = p >> 1, mh = p & 1;
      const int ka = (ks * 64 + lg * 16) ^ kswz;
      // ds_read this phase's fragments
      bf16x8 aF[4];
      #pragma unroll
      for (int mi = 0; mi < 4; ++mi)
        aF[mi] = *(const bf16x8*)(sAb + (wr * 128 + mh * 64 + mi * 16 + lm) * 128 + ka);
      if (mh == 0) {
        #pragma unroll
        for (int ni = 0; ni < 4; ++ni)
          bF[ni] = *(const bf16x8*)(sBb + (wc * 64 + ni * 16 + lm) * 128 + ka);
      }
      // prefetch 2 sweeps of next tile
      if (kt < 15) {
        gll16(pa + (size_t)(p * 64) * 1024 + k0n, dAn + p * 8192 + t * 16);
        gll16(pb + (size_t)(p * 64) * 1024 + k0n, dBn + p * 8192 + t * 16);
      }
      __builtin_amdgcn_s_barrier();
      asm volatile("s_waitcnt lgkmcnt(0)" ::: "memory");
      __builtin_amdgcn_sched_barrier(0);
      __builtin_amdgcn_s_setprio(1);
      #pragma unroll
      for (int mi = 0; mi < 4; ++mi)
        #pragma unroll
        for (int ni = 0; ni < 4; ++ni)
          acc[mh * 4 + mi][ni] =
              __builtin_amdgcn_mfma_f32_16x16x32_bf16(aF[mi], bF[ni], acc[mh * 4 + mi][ni], 0, 0, 0);
      __builtin_amdgcn_s_setprio(0);
      if (p < 3) __builtin_amdgcn_s_barrier();
    }
    if (kt < 15) {
      asm volatile("s_waitcnt vmcnt(0)" ::: "memory");  // next tile landed (issued >=1 phase ago)
      __builtin_amdgcn_s_barrier();
    }
    buf ^= 1;
  }

  // epilogue: out = gamma*acc + x
  const float g0 = gam[0];
  #pragma unroll
  for (int mi8 = 0; mi8 < 8; ++mi8) {
    const int rbase = m0 + wr * 128 + (mi8 >> 2) * 64 + (mi8 & 3) * 16 + lg * 4;
    #pragma unroll
    for (int j = 0; j < 4; ++j) {
      const size_t ro = (size_t)(rbase + j) * 1024;
      #pragma unroll
      for (int ni = 0; ni < 4; ++ni) {
        const int col = n0 + wc * 64 + ni * 16 + lm;
        out[ro + col] = g0 * acc[mi8][ni][j] + x[ro + col];
      }
    }
  }
}

extern "C" void kernel_launch(void* const* d_in, const int* in_sizes, int n_in,
                              void* d_out, int out_size, void* d_ws, size_t ws_size,
                              hipStream_t stream) {
  const float* x  = (const float*)d_in[0];
  const float* Wq = (const float*)d_in[1];
  const float* bq = (const float*)d_in[2];
  const float* Wk = (const float*)d_in[3];
  const float* bk = (const float*)d_in[4];
  const float* Wv = (const float*)d_in[5];
  const float* bv = (const float*)d_in[6];
  const float* gm = (const float*)d_in[7];
  float* out = (float*)d_out;

  char* ws = (char*)d_ws;
  u16*   wt = (u16*)(ws);                 // 2,621,440 B
  float* bc = (float*)(ws + 2621440);     // 5,120 B
  u16*   qk = (u16*)(ws + 2626560);       // 16,777,216 B
  u16*   vt = (u16*)(ws + 19403776);      // 67,108,864 B
  u16*   Pm = (u16*)(ws + 86512640);      // 67,108,864 B
  u16*   xb = (u16*)(ws + 153621504);     // 67,108,864 B

  xbf_k<<<16384, 256, 0, stream>>>(x, xb);
  build_bias_k<<<5, 256, 0, stream>>>(bq, bk, bv, bc);
  transpose_w_k<<<dim3(20, 16), 256, 0, stream>>>(Wq, Wk, Wv, wt);
  gemm_qkv_k<<<dim3(512), 256, 0, stream>>>(xb, wt, bc, qk, vt);
  qks_k<<<dim3(1024), 512, 0, stream>>>(qk, Pm);
  pv_k<<<dim3(512), 512, 0, stream>>>(Pm, vt, x, gm, out);
}

// Round 9
// 296.306 us; speedup vs baseline: 1.0984x; 1.0984x over previous
//
#include <hip/hip_runtime.h>

typedef unsigned short u16;
typedef __attribute__((ext_vector_type(8))) short bf16x8;
typedef __attribute__((ext_vector_type(4))) float f32x4;

__device__ __forceinline__ u16 f2bf(float f) {
  unsigned u = __builtin_bit_cast(unsigned, f);
  u += 0x7fffu + ((u >> 16) & 1u);
  return (u16)(u >> 16);
}

__device__ __forceinline__ float bf2f(u16 h) {
  unsigned u = ((unsigned)h) << 16;
  return __builtin_bit_cast(float, u);
}

__device__ __forceinline__ unsigned pkbf(float lo, float hi) {
  unsigned r;
  asm("v_cvt_pk_bf16_f32 %0, %1, %2" : "=v"(r) : "v"(lo), "v"(hi));
  return r;
}

__device__ __forceinline__ void gll16(const void* g, void* l) {
  __builtin_amdgcn_global_load_lds((const __attribute__((address_space(1))) void*)g,
                                   (__attribute__((address_space(3))) void*)l, 16, 0, 0);
}

// ---------------- x -> bf16 (one-time) ----------------
__global__ void xbf_k(const float* __restrict__ x, u16* __restrict__ xb) {
  const size_t i = ((size_t)blockIdx.x * 256 + threadIdx.x) * 8;
  float4 a = *(const float4*)(x + i);
  float4 b = *(const float4*)(x + i + 4);
  uint4 u;
  u.x = pkbf(a.x, a.y);
  u.y = pkbf(a.z, a.w);
  u.z = pkbf(b.x, b.y);
  u.w = pkbf(b.z, b.w);
  *(uint4*)(xb + i) = u;
}

// ---------------- bias concat: bc[1280] = [bq | bk | bv] ----------------
__global__ void build_bias_k(const float* __restrict__ bq, const float* __restrict__ bk,
                             const float* __restrict__ bv, float* __restrict__ bc) {
  int i = blockIdx.x * 256 + threadIdx.x;
  if (i < 1280) bc[i] = (i < 128) ? bq[i] : ((i < 256) ? bk[i - 128] : bv[i - 256]);
}

// ------- weight transpose: wt[n][f] bf16, n in [0,1280), f in [0,1024) -------
__global__ void transpose_w_k(const float* __restrict__ Wq, const float* __restrict__ Wk,
                              const float* __restrict__ Wv, u16* __restrict__ wt) {
  __shared__ float tile[64][65];
  const int n0 = blockIdx.x * 64;
  const int f0 = blockIdx.y * 64;
  const int t = threadIdx.x;
  const float* src; int ld, coff;
  if (n0 < 128)      { src = Wq; ld = 128;  coff = n0; }
  else if (n0 < 256) { src = Wk; ld = 128;  coff = n0 - 128; }
  else               { src = Wv; ld = 1024; coff = n0 - 256; }
  const int r = t >> 4, c4 = (t & 15) * 4;
  #pragma unroll
  for (int i = 0; i < 4; ++i) {
    float4 v = *(const float4*)(src + (size_t)(f0 + r + 16 * i) * ld + coff + c4);
    tile[r + 16 * i][c4 + 0] = v.x;
    tile[r + 16 * i][c4 + 1] = v.y;
    tile[r + 16 * i][c4 + 2] = v.z;
    tile[r + 16 * i][c4 + 3] = v.w;
  }
  __syncthreads();
  #pragma unroll
  for (int i = 0; i < 4; ++i) {
    const int nr = r + 16 * i;
    ushort4 h;
    h.x = f2bf(tile[c4 + 0][nr]);
    h.y = f2bf(tile[c4 + 1][nr]);
    h.z = f2bf(tile[c4 + 2][nr]);
    h.w = f2bf(tile[c4 + 3][nr]);
    *(ushort4*)(wt + (size_t)(n0 + nr) * 1024 + f0 + c4) = h;
  }
}

// ---------------- fused QKV GEMM: [32768,1024]bf16 @ [1024,1280] + bias ----------------
// 512 blocks: paired decode puts the 2 y-groups sharing an x slab on the same XCD.
// Single 32KB LDS buffer, plain 2-barrier loop -> max blocks/CU; TLP hides the drain (m114).
__global__ __launch_bounds__(256, 2) void gemm_qkv_k(
    const u16* __restrict__ xb, const u16* __restrict__ wt,
    const float* __restrict__ bc, u16* __restrict__ qkv, u16* __restrict__ vt) {
  __shared__ u16 sA[128 * 64];
  __shared__ u16 sB[128 * 64];
  char* sAc = (char*)sA;
  char* sBc = (char*)sB;
  const int t = threadIdx.x;
  const int w = t >> 6, lane = t & 63;
  const int wr = w >> 1, wc = w & 1;
  const int lm = lane & 15, lg = lane >> 4;
  const int bid = blockIdx.x;
  const int mb = ((bid & ~15) >> 1) | (bid & 7);  // 0..255
  const int yg = (bid >> 3) & 1;
  const int m0 = mb * 128;
  const f32x4 FZ = {0.f, 0.f, 0.f, 0.f};

  const int brow = t >> 3;
  const int bcol = 8 * ((t & 7) ^ ((t >> 3) & 7));
  const int kswz = (lm & 7) << 4;
  const u16* ab = xb + (size_t)(m0 + brow) * 1024 + bcol;

  for (int nt = yg * 5; nt < yg * 5 + 5; ++nt) {
    const int n0 = nt * 128;
    f32x4 acc[4][4];
    #pragma unroll
    for (int mi = 0; mi < 4; ++mi)
      #pragma unroll
      for (int ni = 0; ni < 4; ++ni) acc[mi][ni] = FZ;
    const u16* wb = wt + (size_t)(n0 + brow) * 1024 + bcol;

    for (int kt = 0; kt < 16; ++kt) {
      const int k0 = kt * 64;
      char* da = sAc + w * 1024;
      char* db = sBc + w * 1024;
      #pragma unroll
      for (int i = 0; i < 4; ++i) {
        gll16(ab + (size_t)(32 * i) * 1024 + k0, da + 4096 * i);
        gll16(wb + (size_t)(32 * i) * 1024 + k0, db + 4096 * i);
      }
      __syncthreads();
      #pragma unroll
      for (int ks = 0; ks < 2; ++ks) {
        const int ka = (ks * 64 + lg * 16) ^ kswz;
        bf16x8 aF[4], bF[4];
        #pragma unroll
        for (int mi = 0; mi < 4; ++mi)
          aF[mi] = *(const bf16x8*)(sAc + (wr * 64 + mi * 16 + lm) * 128 + ka);
        #pragma unroll
        for (int ni = 0; ni < 4; ++ni)
          bF[ni] = *(const bf16x8*)(sBc + (wc * 64 + ni * 16 + lm) * 128 + ka);
        #pragma unroll
        for (int mi = 0; mi < 4; ++mi)
          #pragma unroll
          for (int ni = 0; ni < 4; ++ni)
            acc[mi][ni] = __builtin_amdgcn_mfma_f32_16x16x32_bf16(aF[mi], bF[ni], acc[mi][ni], 0, 0, 0);
      }
      __syncthreads();
    }

    #pragma unroll
    for (int ni = 0; ni < 4; ++ni) {
      const int col = n0 + wc * 64 + ni * 16 + lm;
      const float bias = bc[col];
      if (n0 < 256) {
        #pragma unroll
        for (int mi = 0; mi < 4; ++mi) {
          const int r0 = m0 + wr * 64 + mi * 16 + lg * 4;
          #pragma unroll
          for (int j = 0; j < 4; ++j)
            qkv[(size_t)(r0 + j) * 256 + col] = f2bf(acc[mi][ni][j] + bias);
        }
      } else {
        const int h = col - 256;
        #pragma unroll
        for (int mi = 0; mi < 4; ++mi) {
          const int r0 = m0 + wr * 64 + mi * 16 + lg * 4;
          const int bg = r0 >> 10;
          const int sb = r0 & 1023;
          ushort4 pk;
          pk.x = f2bf(acc[mi][ni][0] + bias);
          pk.y = f2bf(acc[mi][ni][1] + bias);
          pk.z = f2bf(acc[mi][ni][2] + bias);
          pk.w = f2bf(acc[mi][ni][3] + bias);
          *(ushort4*)(vt + ((size_t)(bg * 1024 + h) << 10) + sb) = pk;
        }
      }
    }
  }
}

// ---------------- QK^T + exact softmax -> normalized P (bf16) ----------------
__global__ __launch_bounds__(512, 2) void qks_k(const u16* __restrict__ qk,
                                                u16* __restrict__ P) {
  __shared__ float smax[8][32];
  __shared__ float ssum[8][32];
  const int t = threadIdx.x;
  const int w = t >> 6, lane = t & 63;
  const int lm = lane & 15, lg = lane >> 4;
  const int bid = blockIdx.x;
  const int qt = (bid >> 3) & 31;
  const int bg = (((bid >> 8) & 3) << 3) | (bid & 7);
  const f32x4 FZ = {0.f, 0.f, 0.f, 0.f};

  bf16x8 qf[2][4];
  #pragma unroll
  for (int qc = 0; qc < 2; ++qc)
    #pragma unroll
    for (int ks = 0; ks < 4; ++ks)
      qf[qc][ks] = *(const bf16x8*)(qk +
          (size_t)(bg * 1024 + qt * 32 + qc * 16 + lm) * 256 + ks * 32 + lg * 8);

  f32x4 sc[8][2];
  #pragma unroll
  for (int ch = 0; ch < 8; ++ch) { sc[ch][0] = FZ; sc[ch][1] = FZ; }
  const u16* kbase = qk + (size_t)(bg * 1024 + w * 128) * 256 + 128;
  #pragma unroll
  for (int ch = 0; ch < 8; ++ch) {
    bf16x8 kf[4];
    #pragma unroll
    for (int ks = 0; ks < 4; ++ks)
      kf[ks] = *(const bf16x8*)(kbase + (size_t)(ch * 16 + lm) * 256 + ks * 32 + lg * 8);
    #pragma unroll
    for (int ks = 0; ks < 4; ++ks) {
      sc[ch][0] = __builtin_amdgcn_mfma_f32_16x16x32_bf16(kf[ks], qf[0][ks], sc[ch][0], 0, 0, 0);
      sc[ch][1] = __builtin_amdgcn_mfma_f32_16x16x32_bf16(kf[ks], qf[1][ks], sc[ch][1], 0, 0, 0);
    }
  }

  float mx[2];
  #pragma unroll
  for (int qc = 0; qc < 2; ++qc) {
    float m = sc[0][qc][0];
    #pragma unroll
    for (int ch = 0; ch < 8; ++ch)
      #pragma unroll
      for (int j = 0; j < 4; ++j) m = fmaxf(m, sc[ch][qc][j]);
    m = fmaxf(m, __shfl_xor(m, 16));
    m = fmaxf(m, __shfl_xor(m, 32));
    mx[qc] = m;
  }
  if (lg == 0) { smax[w][lm] = mx[0]; smax[w][16 + lm] = mx[1]; }
  __syncthreads();
  float gm[2];
  #pragma unroll
  for (int qc = 0; qc < 2; ++qc) {
    float m = smax[0][qc * 16 + lm];
    #pragma unroll
    for (int wp = 1; wp < 8; ++wp) m = fmaxf(m, smax[wp][qc * 16 + lm]);
    gm[qc] = m;
  }

  float ls[2] = {0.f, 0.f};
  #pragma unroll
  for (int ch = 0; ch < 8; ++ch)
    #pragma unroll
    for (int qc = 0; qc < 2; ++qc) {
      f32x4 e;
      #pragma unroll
      for (int j = 0; j < 4; ++j) e[j] = __expf(sc[ch][qc][j] - gm[qc]);
      sc[ch][qc] = e;
      ls[qc] += (e[0] + e[1]) + (e[2] + e[3]);
    }
  #pragma unroll
  for (int qc = 0; qc < 2; ++qc) {
    ls[qc] += __shfl_xor(ls[qc], 16);
    ls[qc] += __shfl_xor(ls[qc], 32);
  }
  if (lg == 0) { ssum[w][lm] = ls[0]; ssum[w][16 + lm] = ls[1]; }
  __syncthreads();
  float inv[2];
  #pragma unroll
  for (int qc = 0; qc < 2; ++qc) {
    float s = ssum[0][qc * 16 + lm];
    #pragma unroll
    for (int wp = 1; wp < 8; ++wp) s += ssum[wp][qc * 16 + lm];
    inv[qc] = 1.0f / s;
  }

  #pragma unroll
  for (int qc = 0; qc < 2; ++qc) {
    u16* pr = P + ((size_t)(bg * 1024 + qt * 32 + qc * 16 + lm) << 10) + w * 128 + lg * 4;
    #pragma unroll
    for (int ch = 0; ch < 8; ++ch) {
      uint2 u;
      u.x = pkbf(sc[ch][qc][0] * inv[qc], sc[ch][qc][1] * inv[qc]);
      u.y = pkbf(sc[ch][qc][2] * inv[qc], sc[ch][qc][3] * inv[qc]);
      *(uint2*)(pr + ch * 16) = u;
    }
  }
}

// ---------------- PV GEMM + epilogue: out = gamma * (P @ V) + xb ----------------
// r6 structure: 128x128xBK64, single 32KB LDS, plain 2-barrier loop, 2048 blocks (high TLP).
// Residual read from bf16 xb (L3-hot) instead of fp32 x.
__global__ __launch_bounds__(256, 2) void pv_k(
    const u16* __restrict__ P, const u16* __restrict__ vt,
    const u16* __restrict__ xb, const float* __restrict__ gam,
    float* __restrict__ out) {
  __shared__ u16 sA[128 * 64];
  __shared__ u16 sB[128 * 64];
  char* sAc = (char*)sA;
  char* sBc = (char*)sB;
  const int t = threadIdx.x;
  const int w = t >> 6, lane = t & 63;
  const int wr = w >> 1, wc = w & 1;
  const int lm = lane & 15, lg = lane >> 4;
  const int bid = blockIdx.x;
  const int bg = (((bid >> 9) & 3) << 3) | (bid & 7);
  const int qb = (bid >> 6) & 7;
  const int hb = (bid >> 3) & 7;
  const int m0 = qb * 128, n0 = hb * 128;
  const f32x4 FZ = {0.f, 0.f, 0.f, 0.f};

  const int brow = t >> 3;
  const int bcol = 8 * ((t & 7) ^ ((t >> 3) & 7));
  const int kswz = (lm & 7) << 4;
  const u16* pb = P + ((size_t)(bg * 1024 + m0 + brow) << 10) + bcol;
  const u16* wb = vt + ((size_t)(bg * 1024 + n0 + brow) << 10) + bcol;

  f32x4 acc[4][4];
  #pragma unroll
  for (int mi = 0; mi < 4; ++mi)
    #pragma unroll
    for (int ni = 0; ni < 4; ++ni) acc[mi][ni] = FZ;

  for (int kt = 0; kt < 16; ++kt) {
    const int k0 = kt * 64;
    char* da = sAc + w * 1024;
    char* db = sBc + w * 1024;
    #pragma unroll
    for (int i = 0; i < 4; ++i) {
      gll16(pb + (size_t)(32 * i) * 1024 + k0, da + 4096 * i);
      gll16(wb + (size_t)(32 * i) * 1024 + k0, db + 4096 * i);
    }
    __syncthreads();
    #pragma unroll
    for (int ks = 0; ks < 2; ++ks) {
      const int ka = (ks * 64 + lg * 16) ^ kswz;
      bf16x8 aF[4], bF[4];
      #pragma unroll
      for (int mi = 0; mi < 4; ++mi)
        aF[mi] = *(const bf16x8*)(sAc + (wr * 64 + mi * 16 + lm) * 128 + ka);
      #pragma unroll
      for (int ni = 0; ni < 4; ++ni)
        bF[ni] = *(const bf16x8*)(sBc + (wc * 64 + ni * 16 + lm) * 128 + ka);
      #pragma unroll
      for (int mi = 0; mi < 4; ++mi)
        #pragma unroll
        for (int ni = 0; ni < 4; ++ni)
          acc[mi][ni] = __builtin_amdgcn_mfma_f32_16x16x32_bf16(aF[mi], bF[ni], acc[mi][ni], 0, 0, 0);
    }
    __syncthreads();
  }

  // epilogue: out = gamma*acc + xb (bf16 residual)
  const float g0 = gam[0];
  #pragma unroll
  for (int mi = 0; mi < 4; ++mi)
    #pragma unroll
    for (int j = 0; j < 4; ++j) {
      const size_t row = (size_t)(bg * 1024 + m0 + wr * 64 + mi * 16 + lg * 4 + j);
      #pragma unroll
      for (int ni = 0; ni < 4; ++ni) {
        const int col = n0 + wc * 64 + ni * 16 + lm;
        const size_t idx = row * 1024 + col;
        out[idx] = g0 * acc[mi][ni][j] + bf2f(xb[idx]);
      }
    }
}

extern "C" void kernel_launch(void* const* d_in, const int* in_sizes, int n_in,
                              void* d_out, int out_size, void* d_ws, size_t ws_size,
                              hipStream_t stream) {
  const float* x  = (const float*)d_in[0];
  const float* Wq = (const float*)d_in[1];
  const float* bq = (const float*)d_in[2];
  const float* Wk = (const float*)d_in[3];
  const float* bk = (const float*)d_in[4];
  const float* Wv = (const float*)d_in[5];
  const float* bv = (const float*)d_in[6];
  const float* gm = (const float*)d_in[7];
  float* out = (float*)d_out;

  char* ws = (char*)d_ws;
  u16*   wt = (u16*)(ws);                 // 2,621,440 B
  float* bc = (float*)(ws + 2621440);     // 5,120 B
  u16*   qk = (u16*)(ws + 2626560);       // 16,777,216 B
  u16*   vt = (u16*)(ws + 19403776);      // 67,108,864 B
  u16*   Pm = (u16*)(ws + 86512640);      // 67,108,864 B
  u16*   xb = (u16*)(ws + 153621504);     // 67,108,864 B

  xbf_k<<<16384, 256, 0, stream>>>(x, xb);
  build_bias_k<<<5, 256, 0, stream>>>(bq, bk, bv, bc);
  transpose_w_k<<<dim3(20, 16), 256, 0, stream>>>(Wq, Wk, Wv, wt);
  gemm_qkv_k<<<dim3(512), 256, 0, stream>>>(xb, wt, bc, qk, vt);
  qks_k<<<dim3(1024), 512, 0, stream>>>(qk, Pm);
  pv_k<<<dim3(2048), 256, 0, stream>>>(Pm, vt, xb, gm, out);
}

// Round 10
// 280.098 us; speedup vs baseline: 1.1619x; 1.0579x over previous
//
#include <hip/hip_runtime.h>

typedef unsigned short u16;
typedef __attribute__((ext_vector_type(8))) short bf16x8;
typedef __attribute__((ext_vector_type(4))) float f32x4;

__device__ __forceinline__ u16 f2bf(float f) {
  unsigned u = __builtin_bit_cast(unsigned, f);
  u += 0x7fffu + ((u >> 16) & 1u);
  return (u16)(u >> 16);
}

__device__ __forceinline__ float bf2f(u16 h) {
  unsigned u = ((unsigned)h) << 16;
  return __builtin_bit_cast(float, u);
}

__device__ __forceinline__ unsigned pkbf(float lo, float hi) {
  unsigned r;
  asm("v_cvt_pk_bf16_f32 %0, %1, %2" : "=v"(r) : "v"(lo), "v"(hi));
  return r;
}

__device__ __forceinline__ void gll16(const void* g, void* l) {
  __builtin_amdgcn_global_load_lds((const __attribute__((address_space(1))) void*)g,
                                   (__attribute__((address_space(3))) void*)l, 16, 0, 0);
}

// ---------------- x -> bf16 (one-time) ----------------
__global__ void xbf_k(const float* __restrict__ x, u16* __restrict__ xb) {
  const size_t i = ((size_t)blockIdx.x * 256 + threadIdx.x) * 8;
  float4 a = *(const float4*)(x + i);
  float4 b = *(const float4*)(x + i + 4);
  uint4 u;
  u.x = pkbf(a.x, a.y);
  u.y = pkbf(a.z, a.w);
  u.z = pkbf(b.x, b.y);
  u.w = pkbf(b.z, b.w);
  *(uint4*)(xb + i) = u;
}

// ---------------- bias concat: bc[1280] = [bq | bk | bv] ----------------
__global__ void build_bias_k(const float* __restrict__ bq, const float* __restrict__ bk,
                             const float* __restrict__ bv, float* __restrict__ bc) {
  int i = blockIdx.x * 256 + threadIdx.x;
  if (i < 1280) bc[i] = (i < 128) ? bq[i] : ((i < 256) ? bk[i - 128] : bv[i - 256]);
}

// ------- weight transpose: wt[n][f] bf16, n in [0,1280), f in [0,1024) -------
__global__ void transpose_w_k(const float* __restrict__ Wq, const float* __restrict__ Wk,
                              const float* __restrict__ Wv, u16* __restrict__ wt) {
  __shared__ float tile[64][65];
  const int n0 = blockIdx.x * 64;
  const int f0 = blockIdx.y * 64;
  const int t = threadIdx.x;
  const float* src; int ld, coff;
  if (n0 < 128)      { src = Wq; ld = 128;  coff = n0; }
  else if (n0 < 256) { src = Wk; ld = 128;  coff = n0 - 128; }
  else               { src = Wv; ld = 1024; coff = n0 - 256; }
  const int r = t >> 4, c4 = (t & 15) * 4;
  #pragma unroll
  for (int i = 0; i < 4; ++i) {
    float4 v = *(const float4*)(src + (size_t)(f0 + r + 16 * i) * ld + coff + c4);
    tile[r + 16 * i][c4 + 0] = v.x;
    tile[r + 16 * i][c4 + 1] = v.y;
    tile[r + 16 * i][c4 + 2] = v.z;
    tile[r + 16 * i][c4 + 3] = v.w;
  }
  __syncthreads();
  #pragma unroll
  for (int i = 0; i < 4; ++i) {
    const int nr = r + 16 * i;
    ushort4 h;
    h.x = f2bf(tile[c4 + 0][nr]);
    h.y = f2bf(tile[c4 + 1][nr]);
    h.z = f2bf(tile[c4 + 2][nr]);
    h.w = f2bf(tile[c4 + 3][nr]);
    *(ushort4*)(wt + (size_t)(n0 + nr) * 1024 + f0 + c4) = h;
  }
}

// ---------------- fused QKV GEMM: [32768,1024]bf16 @ [1024,1280] + bias ----------------
// 2560 blocks, one (mb, nt) tile each. XCD decode: the 10 nt-blocks sharing an A slab
// are consecutive bids on ONE XCD -> co-resident, A slab L2-hit. 5 blocks/CU (LDS-capped).
__global__ __launch_bounds__(256, 2) void gemm_qkv_k(
    const u16* __restrict__ xb, const u16* __restrict__ wt,
    const float* __restrict__ bc, u16* __restrict__ qkv, u16* __restrict__ vt) {
  __shared__ u16 sA[128 * 64];
  __shared__ u16 sB[128 * 64];
  char* sAc = (char*)sA;
  char* sBc = (char*)sB;
  const int t = threadIdx.x;
  const int w = t >> 6, lane = t & 63;
  const int wr = w >> 1, wc = w & 1;
  const int lm = lane & 15, lg = lane >> 4;
  const int bid = blockIdx.x;
  const int xcd = bid & 7, g = bid >> 3;       // g in 0..319
  const int mb = xcd + 8 * (g / 10);           // 0..255
  const int nt = g % 10;
  const int m0 = mb * 128;
  const int n0 = nt * 128;
  const f32x4 FZ = {0.f, 0.f, 0.f, 0.f};

  const int brow = t >> 3;
  const int bcol = 8 * ((t & 7) ^ ((t >> 3) & 7));
  const int kswz = (lm & 7) << 4;
  const u16* ab = xb + (size_t)(m0 + brow) * 1024 + bcol;
  const u16* wb = wt + (size_t)(n0 + brow) * 1024 + bcol;

  f32x4 acc[4][4];
  #pragma unroll
  for (int mi = 0; mi < 4; ++mi)
    #pragma unroll
    for (int ni = 0; ni < 4; ++ni) acc[mi][ni] = FZ;

  for (int kt = 0; kt < 16; ++kt) {
    const int k0 = kt * 64;
    char* da = sAc + w * 1024;
    char* db = sBc + w * 1024;
    #pragma unroll
    for (int i = 0; i < 4; ++i) {
      gll16(ab + (size_t)(32 * i) * 1024 + k0, da + 4096 * i);
      gll16(wb + (size_t)(32 * i) * 1024 + k0, db + 4096 * i);
    }
    __syncthreads();
    #pragma unroll
    for (int ks = 0; ks < 2; ++ks) {
      const int ka = (ks * 64 + lg * 16) ^ kswz;
      bf16x8 aF[4], bF[4];
      #pragma unroll
      for (int mi = 0; mi < 4; ++mi)
        aF[mi] = *(const bf16x8*)(sAc + (wr * 64 + mi * 16 + lm) * 128 + ka);
      #pragma unroll
      for (int ni = 0; ni < 4; ++ni)
        bF[ni] = *(const bf16x8*)(sBc + (wc * 64 + ni * 16 + lm) * 128 + ka);
      #pragma unroll
      for (int mi = 0; mi < 4; ++mi)
        #pragma unroll
        for (int ni = 0; ni < 4; ++ni)
          acc[mi][ni] = __builtin_amdgcn_mfma_f32_16x16x32_bf16(aF[mi], bF[ni], acc[mi][ni], 0, 0, 0);
    }
    __syncthreads();
  }

  // epilogue (branch is block-uniform now)
  if (n0 < 256) {
    #pragma unroll
    for (int ni = 0; ni < 4; ++ni) {
      const int col = n0 + wc * 64 + ni * 16 + lm;
      const float bias = bc[col];
      #pragma unroll
      for (int mi = 0; mi < 4; ++mi) {
        const int r0 = m0 + wr * 64 + mi * 16 + lg * 4;
        #pragma unroll
        for (int j = 0; j < 4; ++j)
          qkv[(size_t)(r0 + j) * 256 + col] = f2bf(acc[mi][ni][j] + bias);
      }
    }
  } else {
    #pragma unroll
    for (int ni = 0; ni < 4; ++ni) {
      const int col = n0 + wc * 64 + ni * 16 + lm;
      const float bias = bc[col];
      const int h = col - 256;
      #pragma unroll
      for (int mi = 0; mi < 4; ++mi) {
        const int r0 = m0 + wr * 64 + mi * 16 + lg * 4;
        const int bg = r0 >> 10;
        const int sb = r0 & 1023;
        ushort4 pk;
        pk.x = f2bf(acc[mi][ni][0] + bias);
        pk.y = f2bf(acc[mi][ni][1] + bias);
        pk.z = f2bf(acc[mi][ni][2] + bias);
        pk.w = f2bf(acc[mi][ni][3] + bias);
        *(ushort4*)(vt + ((size_t)(bg * 1024 + h) << 10) + sb) = pk;
      }
    }
  }
}

// ---------------- QK^T + exact softmax -> normalized P (bf16) ----------------
__global__ __launch_bounds__(512, 2) void qks_k(const u16* __restrict__ qk,
                                                u16* __restrict__ P) {
  __shared__ float smax[8][32];
  __shared__ float ssum[8][32];
  const int t = threadIdx.x;
  const int w = t >> 6, lane = t & 63;
  const int lm = lane & 15, lg = lane >> 4;
  const int bid = blockIdx.x;
  const int qt = (bid >> 3) & 31;
  const int bg = (((bid >> 8) & 3) << 3) | (bid & 7);
  const f32x4 FZ = {0.f, 0.f, 0.f, 0.f};

  bf16x8 qf[2][4];
  #pragma unroll
  for (int qc = 0; qc < 2; ++qc)
    #pragma unroll
    for (int ks = 0; ks < 4; ++ks)
      qf[qc][ks] = *(const bf16x8*)(qk +
          (size_t)(bg * 1024 + qt * 32 + qc * 16 + lm) * 256 + ks * 32 + lg * 8);

  f32x4 sc[8][2];
  #pragma unroll
  for (int ch = 0; ch < 8; ++ch) { sc[ch][0] = FZ; sc[ch][1] = FZ; }
  const u16* kbase = qk + (size_t)(bg * 1024 + w * 128) * 256 + 128;
  #pragma unroll
  for (int ch = 0; ch < 8; ++ch) {
    bf16x8 kf[4];
    #pragma unroll
    for (int ks = 0; ks < 4; ++ks)
      kf[ks] = *(const bf16x8*)(kbase + (size_t)(ch * 16 + lm) * 256 + ks * 32 + lg * 8);
    #pragma unroll
    for (int ks = 0; ks < 4; ++ks) {
      sc[ch][0] = __builtin_amdgcn_mfma_f32_16x16x32_bf16(kf[ks], qf[0][ks], sc[ch][0], 0, 0, 0);
      sc[ch][1] = __builtin_amdgcn_mfma_f32_16x16x32_bf16(kf[ks], qf[1][ks], sc[ch][1], 0, 0, 0);
    }
  }

  float mx[2];
  #pragma unroll
  for (int qc = 0; qc < 2; ++qc) {
    float m = sc[0][qc][0];
    #pragma unroll
    for (int ch = 0; ch < 8; ++ch)
      #pragma unroll
      for (int j = 0; j < 4; ++j) m = fmaxf(m, sc[ch][qc][j]);
    m = fmaxf(m, __shfl_xor(m, 16));
    m = fmaxf(m, __shfl_xor(m, 32));
    mx[qc] = m;
  }
  if (lg == 0) { smax[w][lm] = mx[0]; smax[w][16 + lm] = mx[1]; }
  __syncthreads();
  float gm[2];
  #pragma unroll
  for (int qc = 0; qc < 2; ++qc) {
    float m = smax[0][qc * 16 + lm];
    #pragma unroll
    for (int wp = 1; wp < 8; ++wp) m = fmaxf(m, smax[wp][qc * 16 + lm]);
    gm[qc] = m;
  }

  float ls[2] = {0.f, 0.f};
  #pragma unroll
  for (int ch = 0; ch < 8; ++ch)
    #pragma unroll
    for (int qc = 0; qc < 2; ++qc) {
      f32x4 e;
      #pragma unroll
      for (int j = 0; j < 4; ++j) e[j] = __expf(sc[ch][qc][j] - gm[qc]);
      sc[ch][qc] = e;
      ls[qc] += (e[0] + e[1]) + (e[2] + e[3]);
    }
  #pragma unroll
  for (int qc = 0; qc < 2; ++qc) {
    ls[qc] += __shfl_xor(ls[qc], 16);
    ls[qc] += __shfl_xor(ls[qc], 32);
  }
  if (lg == 0) { ssum[w][lm] = ls[0]; ssum[w][16 + lm] = ls[1]; }
  __syncthreads();
  float inv[2];
  #pragma unroll
  for (int qc = 0; qc < 2; ++qc) {
    float s = ssum[0][qc * 16 + lm];
    #pragma unroll
    for (int wp = 1; wp < 8; ++wp) s += ssum[wp][qc * 16 + lm];
    inv[qc] = 1.0f / s;
  }

  #pragma unroll
  for (int qc = 0; qc < 2; ++qc) {
    u16* pr = P + ((size_t)(bg * 1024 + qt * 32 + qc * 16 + lm) << 10) + w * 128 + lg * 4;
    #pragma unroll
    for (int ch = 0; ch < 8; ++ch) {
      uint2 u;
      u.x = pkbf(sc[ch][qc][0] * inv[qc], sc[ch][qc][1] * inv[qc]);
      u.y = pkbf(sc[ch][qc][2] * inv[qc], sc[ch][qc][3] * inv[qc]);
      *(uint2*)(pr + ch * 16) = u;
    }
  }
}

// ---------------- PV GEMM + epilogue: out = gamma * (P @ V) + xb ----------------
__global__ __launch_bounds__(256, 2) void pv_k(
    const u16* __restrict__ P, const u16* __restrict__ vt,
    const u16* __restrict__ xb, const float* __restrict__ gam,
    float* __restrict__ out) {
  __shared__ u16 sA[128 * 64];
  __shared__ u16 sB[128 * 64];
  char* sAc = (char*)sA;
  char* sBc = (char*)sB;
  const int t = threadIdx.x;
  const int w = t >> 6, lane = t & 63;
  const int wr = w >> 1, wc = w & 1;
  const int lm = lane & 15, lg = lane >> 4;
  const int bid = blockIdx.x;
  const int bg = (((bid >> 9) & 3) << 3) | (bid & 7);
  const int qb = (bid >> 6) & 7;
  const int hb = (bid >> 3) & 7;
  const int m0 = qb * 128, n0 = hb * 128;
  const f32x4 FZ = {0.f, 0.f, 0.f, 0.f};

  const int brow = t >> 3;
  const int bcol = 8 * ((t & 7) ^ ((t >> 3) & 7));
  const int kswz = (lm & 7) << 4;
  const u16* pb = P + ((size_t)(bg * 1024 + m0 + brow) << 10) + bcol;
  const u16* wb = vt + ((size_t)(bg * 1024 + n0 + brow) << 10) + bcol;

  f32x4 acc[4][4];
  #pragma unroll
  for (int mi = 0; mi < 4; ++mi)
    #pragma unroll
    for (int ni = 0; ni < 4; ++ni) acc[mi][ni] = FZ;

  for (int kt = 0; kt < 16; ++kt) {
    const int k0 = kt * 64;
    char* da = sAc + w * 1024;
    char* db = sBc + w * 1024;
    #pragma unroll
    for (int i = 0; i < 4; ++i) {
      gll16(pb + (size_t)(32 * i) * 1024 + k0, da + 4096 * i);
      gll16(wb + (size_t)(32 * i) * 1024 + k0, db + 4096 * i);
    }
    __syncthreads();
    #pragma unroll
    for (int ks = 0; ks < 2; ++ks) {
      const int ka = (ks * 64 + lg * 16) ^ kswz;
      bf16x8 aF[4], bF[4];
      #pragma unroll
      for (int mi = 0; mi < 4; ++mi)
        aF[mi] = *(const bf16x8*)(sAc + (wr * 64 + mi * 16 + lm) * 128 + ka);
      #pragma unroll
      for (int ni = 0; ni < 4; ++ni)
        bF[ni] = *(const bf16x8*)(sBc + (wc * 64 + ni * 16 + lm) * 128 + ka);
      #pragma unroll
      for (int mi = 0; mi < 4; ++mi)
        #pragma unroll
        for (int ni = 0; ni < 4; ++ni)
          acc[mi][ni] = __builtin_amdgcn_mfma_f32_16x16x32_bf16(aF[mi], bF[ni], acc[mi][ni], 0, 0, 0);
    }
    __syncthreads();
  }

  const float g0 = gam[0];
  #pragma unroll
  for (int mi = 0; mi < 4; ++mi)
    #pragma unroll
    for (int j = 0; j < 4; ++j) {
      const size_t row = (size_t)(bg * 1024 + m0 + wr * 64 + mi * 16 + lg * 4 + j);
      #pragma unroll
      for (int ni = 0; ni < 4; ++ni) {
        const int col = n0 + wc * 64 + ni * 16 + lm;
        const size_t idx = row * 1024 + col;
        out[idx] = g0 * acc[mi][ni][j] + bf2f(xb[idx]);
      }
    }
}

extern "C" void kernel_launch(void* const* d_in, const int* in_sizes, int n_in,
                              void* d_out, int out_size, void* d_ws, size_t ws_size,
                              hipStream_t stream) {
  const float* x  = (const float*)d_in[0];
  const float* Wq = (const float*)d_in[1];
  const float* bq = (const float*)d_in[2];
  const float* Wk = (const float*)d_in[3];
  const float* bk = (const float*)d_in[4];
  const float* Wv = (const float*)d_in[5];
  const float* bv = (const float*)d_in[6];
  const float* gm = (const float*)d_in[7];
  float* out = (float*)d_out;

  char* ws = (char*)d_ws;
  u16*   wt = (u16*)(ws);                 // 2,621,440 B
  float* bc = (float*)(ws + 2621440);     // 5,120 B
  u16*   qk = (u16*)(ws + 2626560);       // 16,777,216 B
  u16*   vt = (u16*)(ws + 19403776);      // 67,108,864 B
  u16*   Pm = (u16*)(ws + 86512640);      // 67,108,864 B
  u16*   xb = (u16*)(ws + 153621504);     // 67,108,864 B

  xbf_k<<<16384, 256, 0, stream>>>(x, xb);
  build_bias_k<<<5, 256, 0, stream>>>(bq, bk, bv, bc);
  transpose_w_k<<<dim3(20, 16), 256, 0, stream>>>(Wq, Wk, Wv, wt);
  gemm_qkv_k<<<dim3(2560), 256, 0, stream>>>(xb, wt, bc, qk, vt);
  qks_k<<<dim3(1024), 512, 0, stream>>>(qk, Pm);
  pv_k<<<dim3(2048), 256, 0, stream>>>(Pm, vt, xb, gm, out);
}